// Round 12
// baseline (117.165 us; speedup 1.0000x reference)
//
#include <hip/hip_runtime.h>
#include <hip/hip_bf16.h>

#define S_LEN 4096
#define DHD   64
#define NH    16
#define NKT   64
#define KVB   64
#define WQ    32
#define NW    4
#define QB    (WQ * NW)   // 128
#define QSCALE 0.18033688011112042f   // (1/8) * log2(e) folded into Q
#define THRS   8.656170245333781f     // defer-max threshold: 6 nats in log2 domain

typedef __bf16 bf16x8 __attribute__((ext_vector_type(8)));
typedef __bf16 bf16x4 __attribute__((ext_vector_type(4)));
typedef float  f32x16 __attribute__((ext_vector_type(16)));
typedef float  f32x4  __attribute__((ext_vector_type(4)));
typedef unsigned u32;
typedef unsigned u32x4v __attribute__((ext_vector_type(4)));
typedef unsigned long long u64;

#define MFMA32 __builtin_amdgcn_mfma_f32_32x32x16_bf16

__device__ __forceinline__ float fexp2(float x) {
  float r;
  asm("v_exp_f32 %0, %1" : "=v"(r) : "v"(x));
  return r;
}
#define EXP2(x) fexp2(x)

// XOR swizzle (G4): element = row*64 + (((col>>3) ^ (row&7))<<3 | (col&7))
__device__ __forceinline__ int swz(int row, int col) {
  return row * 64 + ((((col >> 3) ^ (row & 7)) << 3) | (col & 7));
}

__device__ __forceinline__ u32 pk(float a, float b) {   // pack 2 f32 -> 2 bf16 (RNE)
  __bf16 x = (__bf16)a, y = (__bf16)b;
  u32 lo = (u32)__builtin_bit_cast(unsigned short, x);
  u32 hi = (u32)__builtin_bit_cast(unsigned short, y);
  return lo | (hi << 16);
}

__device__ __forceinline__ void gload16(const void* g, void* l) {
  __builtin_amdgcn_global_load_lds((const __attribute__((address_space(1))) void*)g,
                                   (__attribute__((address_space(3))) void*)l, 16, 0, 0);
}

__device__ __forceinline__ void plswap(u32& x, u32& y) {
  asm("v_permlane32_swap_b32 %0, %1" : "+v"(x), "+v"(y));
}

union PAW { u32x4v w; bf16x8 h; };

template <int MODE>
__device__ __forceinline__ bool patget(const void* __restrict__ p, int q, int k) {
  const size_t idx = (size_t)q * S_LEN + k;
  if constexpr (MODE == 1) return ((const unsigned char*)p)[idx] != 0;
  else if constexpr (MODE == 0) return ((const int*)p)[idx] != 0;
  else return ((const float*)p)[idx] != 0.0f;
}

// ============ FAT-WAVE K-split kernel: 64 q-rows/wave, 2 waves/block, split x2 ============
// LDS-read-bound fix (R11 analysis): each K/V fragment read from LDS feeds TWO MFMAs
// (q-set0 + q-set1) -> per-(q,key) LDS traffic halves. Block = 128 thr; grid 1024;
// 4 blocks/CU (LDS 32KB) -> 2 waves/SIMD. Per wave per iter: 2 pw + 8 gload -> vmcnt(10).
__global__ void __launch_bounds__(128, 2) attn64s(
    const float* __restrict__ Qg, const __bf16* __restrict__ Kc, const __bf16* __restrict__ Vc,
    const u64* __restrict__ packw, const int* __restrict__ mask,
    float* __restrict__ O0, float* __restrict__ Opart,
    float* __restrict__ l0a, float* __restrict__ m0a,
    float* __restrict__ l1a, float* __restrict__ m1a) {
  __shared__ __align__(16) __bf16 Kls[2][4096];
  __shared__ __align__(16) __bf16 Vls[2][4096];
  __shared__ float sfb[2][2][32];   // [wave][set][qcol]
  __shared__ int msum[2];

  // XCD-chunked swizzle: 128 consecutive wgids (= 2 heads) per XCD
  const int wgid = (blockIdx.x & 7) * 128 + (blockIdx.x >> 3);
  const int h = wgid >> 6;
  const int q0 = ((wgid >> 1) & 31) * 128;
  const int split = wgid & 1;

  const int t = threadIdx.x, lane = t & 63, wv = t >> 6;   // wv 0..1
  const int l32 = lane & 31, hi = lane >> 5;
  const int qrow0 = q0 + wv * 64 + l32;    // q-set 0
  const int qrow1 = qrow0 + 32;            // q-set 1

  // ---- self-compute active-key count from mask (16KB, L2-hot) ----
  int c = 0;
#pragma unroll
  for (int j = 0; j < 32; j++) c += (mask[t * 32 + j] != 0);
#pragma unroll
  for (int d = 1; d < 64; d <<= 1) c += __shfl_xor(c, d);
  if (lane == 0) msum[wv] = c;

  // Q B-fragments for both q-sets
  bf16x8 aQ0[4], aQ1[4];
  {
    const float* qp0 = Qg + ((size_t)h * S_LEN + qrow0) * DHD;
    const float* qp1 = Qg + ((size_t)h * S_LEN + qrow1) * DHD;
#pragma unroll
    for (int cc = 0; cc < 4; cc++) {
      float4 x = *(const float4*)(qp0 + cc * 16 + hi * 8);
      float4 y = *(const float4*)(qp0 + cc * 16 + hi * 8 + 4);
      bf16x8 f;
      f[0] = (__bf16)(x.x * QSCALE); f[1] = (__bf16)(x.y * QSCALE);
      f[2] = (__bf16)(x.z * QSCALE); f[3] = (__bf16)(x.w * QSCALE);
      f[4] = (__bf16)(y.x * QSCALE); f[5] = (__bf16)(y.y * QSCALE);
      f[6] = (__bf16)(y.z * QSCALE); f[7] = (__bf16)(y.w * QSCALE);
      aQ0[cc] = f;
      x = *(const float4*)(qp1 + cc * 16 + hi * 8);
      y = *(const float4*)(qp1 + cc * 16 + hi * 8 + 4);
      f[0] = (__bf16)(x.x * QSCALE); f[1] = (__bf16)(x.y * QSCALE);
      f[2] = (__bf16)(x.z * QSCALE); f[3] = (__bf16)(x.w * QSCALE);
      f[4] = (__bf16)(y.x * QSCALE); f[5] = (__bf16)(y.y * QSCALE);
      f[6] = (__bf16)(y.z * QSCALE); f[7] = (__bf16)(y.w * QSCALE);
      aQ1[cc] = f;
    }
  }
  f32x16 zv;
#pragma unroll
  for (int r = 0; r < 16; r++) zv[r] = 0.f;

  __syncthreads();
  const int nact = msum[0] + msum[1];
  const int nt = (nact + 63) >> 6;
  const int nh0 = (nt + 1) >> 1;
  const int t0 = split ? nh0 : 0;
  const int t1 = split ? nt : nh0;

  const __bf16* Kb = Kc + (size_t)h * NKT * 4096;
  const __bf16* Vb = Vc + (size_t)h * NKT * 4096;

  // stage: 128 threads x 8 gload16 = 16KB (K 8KB + V 8KB). dst is wave-uniform base
  // + lane*16 within each inst (slot s = i*128 + t -> base per (i,wave), lane-contig).
  auto stage = [&](int buf, int kt) {
    const __bf16* kbase = Kb + (size_t)kt * 4096;
    const __bf16* vbase = Vb + (size_t)kt * 4096;
#pragma unroll
    for (int i = 0; i < 4; i++) {
      const int s = i * 128 + t;
      gload16(kbase + s * 8, &Kls[buf][s * 8]);
    }
#pragma unroll
    for (int i = 0; i < 4; i++) {
      const int s = i * 128 + t;
      gload16(vbase + s * 8, &Vls[buf][s * 8]);
    }
  };

  f32x16 Oc00 = zv, Oc01 = zv, Oc10 = zv, Oc11 = zv;
  float m0_run = -__builtin_inff(), l0_run = 0.f;
  float m1_run = -__builtin_inff(), l1_run = 0.f;
  const u64* prow0 = packw + qrow0;
  const u64* prow1 = packw + qrow1;

  __builtin_amdgcn_sched_barrier(0);
  u64 pw0 = 0, pw1 = 0, pw0_n = 0, pw1_n = 0;
  int cur = 0;
  if (t0 < t1) {
    pw0 = prow0[(size_t)t0 * S_LEN];
    pw1 = prow1[(size_t)t0 * S_LEN];
    stage(0, t0);
  }

  for (int kt = t0; kt < t1; kt++) {
    if (kt + 1 < t1) {
      pw0_n = prow0[(size_t)(kt + 1) * S_LEN];
      pw1_n = prow1[(size_t)(kt + 1) * S_LEN];
      stage(cur ^ 1, kt + 1);
      asm volatile("s_waitcnt vmcnt(10)" ::: "memory");  // prev iter's 10 vmem done
    } else {
      asm volatile("s_waitcnt vmcnt(0)" ::: "memory");
    }
    __builtin_amdgcn_s_barrier();
    __builtin_amdgcn_sched_barrier(0);   // rule #18

    const __bf16* Kl = Kls[cur];
    const __bf16* Vl = Vls[cur];

    // ---- S^T for BOTH q-sets: each K fragment feeds 2 MFMAs (the LDS-halving) ----
    f32x16 p00, p01, p10, p11;
    __builtin_amdgcn_s_setprio(1);
#pragma unroll
    for (int cc = 0; cc < 4; cc++) {
      const int g = (((2 * cc + hi) ^ (l32 & 7)) << 3);
      const bf16x8 k0 = *(const bf16x8*)&Kl[l32 * 64 + g];
      const bf16x8 k1 = *(const bf16x8*)&Kl[(32 + l32) * 64 + g];
      p00 = MFMA32(k0, aQ0[cc], cc ? p00 : zv, 0, 0, 0);
      p01 = MFMA32(k1, aQ0[cc], cc ? p01 : zv, 0, 0, 0);
      p10 = MFMA32(k0, aQ1[cc], cc ? p10 : zv, 0, 0, 0);
      p11 = MFMA32(k1, aQ1[cc], cc ? p11 : zv, 0, 0, 0);
    }
    __builtin_amdgcn_s_setprio(0);

    // ---- tree max per set ----
    float mx[16], my[16];
#pragma unroll
    for (int i = 0; i < 8; i++) {
      mx[i]     = fmaxf(p00[2 * i], p00[2 * i + 1]);
      mx[8 + i] = fmaxf(p01[2 * i], p01[2 * i + 1]);
      my[i]     = fmaxf(p10[2 * i], p10[2 * i + 1]);
      my[8 + i] = fmaxf(p11[2 * i], p11[2 * i + 1]);
    }
#pragma unroll
    for (int s = 8; s >= 1; s >>= 1)
#pragma unroll
      for (int i = 0; i < s; i++) {
        mx[i] = fmaxf(mx[i], mx[i + s]);
        my[i] = fmaxf(my[i], my[i + s]);
      }
    const float pm0 = fmaxf(mx[0], __shfl_xor(mx[0], 32));
    const float pm1 = fmaxf(my[0], __shfl_xor(my[0], 32));

    if (!__all((pm0 <= m0_run + THRS) && (pm1 <= m1_run + THRS))) {   // defer-max (T13)
      const float mn0 = fmaxf(m0_run, pm0);
      const float mn1 = fmaxf(m1_run, pm1);
      const float sf0 = EXP2(m0_run - mn0);
      const float sf1 = EXP2(m1_run - mn1);
      m0_run = mn0; m1_run = mn1;
      l0_run *= sf0; l1_run *= sf1;
      if (lane < 32) { sfb[wv][0][l32] = sf0; sfb[wv][1][l32] = sf1; }
#pragma unroll
      for (int rq = 0; rq < 4; rq++) {
        const f32x4 s40 = *(const f32x4*)&sfb[wv][0][rq * 8 + 4 * hi];
        const f32x4 s41 = *(const f32x4*)&sfb[wv][1][rq * 8 + 4 * hi];
#pragma unroll
        for (int rr = 0; rr < 4; rr++) {
          Oc00[rq * 4 + rr] *= s40[rr];
          Oc01[rq * 4 + rr] *= s40[rr];
          Oc10[rq * 4 + rr] *= s41[rr];
          Oc11[rq * 4 + rr] *= s41[rr];
        }
      }
    }

    // pattern bits per set
    const u32 a0b = (u32)pw0, a1b = (u32)(pw0 >> 32);
    const u32 wA0 = hi ? ((a0b >> 4) | (a1b << 28)) : a0b;
    const u32 wA1 = hi ? (a1b >> 4) : a1b;
    const u32 b0b = (u32)pw1, b1b = (u32)(pw1 >> 32);
    const u32 wB0 = hi ? ((b0b >> 4) | (b1b << 28)) : b0b;
    const u32 wB1 = hi ? (b1b >> 4) : b1b;

    float ls0 = 0.f, ls1 = 0.f;
#pragma unroll
    for (int r = 0; r < 16; r++) {
      const int sp = (r & 3) + 8 * (r >> 2);
      float e00 = EXP2(p00[r] - m0_run);
      float e01 = EXP2(p01[r] - m0_run);
      float e10 = EXP2(p10[r] - m1_run);
      float e11 = EXP2(p11[r] - m1_run);
      const int tA0 = (int)(wA0 << (31 - sp)) >> 31;
      const int tA1 = (int)(wA1 << (31 - sp)) >> 31;
      const int tB0 = (int)(wB0 << (31 - sp)) >> 31;
      const int tB1 = (int)(wB1 << (31 - sp)) >> 31;
      e00 = __uint_as_float(__float_as_uint(e00) & (u32)tA0);
      e01 = __uint_as_float(__float_as_uint(e01) & (u32)tA1);
      e10 = __uint_as_float(__float_as_uint(e10) & (u32)tB0);
      e11 = __uint_as_float(__float_as_uint(e11) & (u32)tB1);
      p00[r] = e00; p01[r] = e01; p10[r] = e10; p11[r] = e11;
      ls0 += e00 + e01;
      ls1 += e10 + e11;
    }
    ls0 += __shfl_xor(ls0, 32);
    ls1 += __shfl_xor(ls1, 32);
    l0_run += ls0;
    l1_run += ls1;

    // ---- pk both sets into A-frags ----
    PAW pa0[4], pa1[4];
#pragma unroll
    for (int ks = 0; ks < 4; ks++) {
      {
        const f32x16& ps = (ks < 2) ? p00 : p01;
        const int b = (ks & 1) * 8;
        u32 x0 = pk(ps[b + 0], ps[b + 1]), x1 = pk(ps[b + 2], ps[b + 3]);
        u32 y0 = pk(ps[b + 4], ps[b + 5]), y1 = pk(ps[b + 6], ps[b + 7]);
        plswap(x0, y0);
        plswap(x1, y1);
        pa0[ks].w = (u32x4v){x0, x1, y0, y1};
      }
      {
        const f32x16& ps = (ks < 2) ? p10 : p11;
        const int b = (ks & 1) * 8;
        u32 x0 = pk(ps[b + 0], ps[b + 1]), x1 = pk(ps[b + 2], ps[b + 3]);
        u32 y0 = pk(ps[b + 4], ps[b + 5]), y1 = pk(ps[b + 6], ps[b + 7]);
        plswap(x0, y0);
        plswap(x1, y1);
        pa1[ks].w = (u32x4v){x0, x1, y0, y1};
      }
    }

    // ---- PV: each V fragment feeds 2 MFMAs (set0 + set1) ----
    __builtin_amdgcn_s_setprio(1);
#pragma unroll
    for (int ks = 0; ks < 4; ks++) {
      const int g = (((2 * ks + hi) ^ (l32 & 7)) << 3);
      const bf16x8 v0 = *(const bf16x8*)&Vl[l32 * 64 + g];
      const bf16x8 v1 = *(const bf16x8*)&Vl[(32 + l32) * 64 + g];
      Oc00 = MFMA32(pa0[ks].h, v0, Oc00, 0, 0, 0);
      Oc01 = MFMA32(pa0[ks].h, v1, Oc01, 0, 0, 0);
      Oc10 = MFMA32(pa1[ks].h, v0, Oc10, 0, 0, 0);
      Oc11 = MFMA32(pa1[ks].h, v1, Oc11, 0, 0, 0);
    }
    __builtin_amdgcn_s_setprio(0);

    __builtin_amdgcn_s_barrier();
    cur ^= 1;
    pw0 = pw0_n;
    pw1 = pw1_n;
  }

  // ---- epilogue: RAW partials for both sets ----
  float* Od = split ? Opart : O0;
  float* lA = split ? l1a : l0a;
  float* mA = split ? m1a : m0a;
  const int rb0 = h * S_LEN + q0 + wv * 64;
  const int rb1 = rb0 + 32;
  if (lane < 32) {
    mA[rb0 + l32] = m0_run;
    lA[rb0 + l32] = l0_run;
    mA[rb1 + l32] = m1_run;
    lA[rb1 + l32] = l1_run;
  }
  float* ob0 = Od + (size_t)rb0 * DHD;
  float* ob1 = Od + (size_t)rb1 * DHD;
#pragma unroll
  for (int rq = 0; rq < 4; rq++) {
#pragma unroll
    for (int rr = 0; rr < 4; rr++) {
      const int r = rq * 4 + rr;
      const int qq = rr + 8 * rq + 4 * hi;
      ob0[(size_t)qq * DHD + l32]      = Oc00[r];
      ob0[(size_t)qq * DHD + 32 + l32] = Oc01[r];
      ob1[(size_t)qq * DHD + l32]      = Oc10[r];
      ob1[(size_t)qq * DHD + 32 + l32] = Oc11[r];
    }
  }
}

// flash-merge: out = (O0*s0 + O1*s1) / (l0*s0 + l1*s1), s_i = 2^(m_i - max(m0,m1))
__global__ void __launch_bounds__(256) merge_k(
    float* __restrict__ out, const float* __restrict__ Op,
    const float* __restrict__ l0a, const float* __restrict__ m0a,
    const float* __restrict__ l1a, const float* __restrict__ m1a) {
  const int gid = blockIdx.x * 256 + threadIdx.x;
  const int row = gid >> 4, c4 = (gid & 15) << 2;
  const float mm0 = m0a[row], mm1 = m1a[row];
  const float mm = fmaxf(mm0, mm1);
  const float s0 = EXP2(mm0 - mm), s1 = EXP2(mm1 - mm);   // exp(-inf)=0: empty split safe
  const float inv = 1.0f / (l0a[row] * s0 + l1a[row] * s1);
  float4* op = (float4*)(out + (size_t)row * DHD + c4);
  const float4 a = *op;
  const float4 b = *(const float4*)(Op + (size_t)row * DHD + c4);
  float4 r;
  r.x = (a.x * s0 + b.x * s1) * inv;
  r.y = (a.y * s0 + b.y * s1) * inv;
  r.z = (a.z * s0 + b.z * s1) * inv;
  r.w = (a.w * s0 + b.w * s1) * inv;
  *op = r;
}

// ===================== mid-tier kernel (R9-proven 2-tile, full K range) ==================
__global__ void __launch_bounds__(256, 2) attn32c2(
    const float* __restrict__ Qg, const __bf16* __restrict__ Kc, const __bf16* __restrict__ Vc,
    const u64* __restrict__ packw, const int* __restrict__ mask, float* __restrict__ out) {
  __shared__ __align__(16) __bf16 Kls[4][KVB * DHD];
  __shared__ __align__(16) __bf16 Vls[4][DHD * KVB];
  __shared__ float sfb[NW][WQ];
  __shared__ int msum[NW];
  const int gid = (blockIdx.x & 7) * 64 + (blockIdx.x >> 3);
  const int h = gid >> 5;
  const int q0 = (gid & 31) * QB;
  const int t = threadIdx.x, lane = t & 63, wv = t >> 6;
  const int l32 = lane & 31, hi = lane >> 5;
  const int qrow = q0 + wv * WQ + l32;
  int c = 0;
#pragma unroll
  for (int j = 0; j < 16; j++) c += (mask[t * 16 + j] != 0);
#pragma unroll
  for (int d = 1; d < 64; d <<= 1) c += __shfl_xor(c, d);
  if (lane == 0) msum[wv] = c;
  bf16x8 aQ[4];
  {
    const float* qp = Qg + ((size_t)h * S_LEN + qrow) * DHD;
#pragma unroll
    for (int cc = 0; cc < 4; cc++) {
      float4 x = *(const float4*)(qp + cc * 16 + hi * 8);
      float4 y = *(const float4*)(qp + cc * 16 + hi * 8 + 4);
      bf16x8 f;
      f[0] = (__bf16)(x.x * QSCALE); f[1] = (__bf16)(x.y * QSCALE);
      f[2] = (__bf16)(x.z * QSCALE); f[3] = (__bf16)(x.w * QSCALE);
      f[4] = (__bf16)(y.x * QSCALE); f[5] = (__bf16)(y.y * QSCALE);
      f[6] = (__bf16)(y.z * QSCALE); f[7] = (__bf16)(y.w * QSCALE);
      aQ[cc] = f;
    }
  }
  bf16x8 onesf;
#pragma unroll
  for (int j = 0; j < 8; j++) onesf[j] = (__bf16)1.0f;
  f32x16 zv;
#pragma unroll
  for (int r = 0; r < 16; r++) zv[r] = 0.f;
  __syncthreads();
  const int nact = msum[0] + msum[1] + msum[2] + msum[3];
  const int nt = (nact + 63) >> 6;
  const int np = ((nt + 1) & ~1) >> 1;
  const __bf16* Kb = Kc + (size_t)h * NKT * 4096;
  const __bf16* Vb = Vc + (size_t)h * NKT * 4096;
  auto stage = [&](int slot, int kt) {
    const __bf16* kbase = Kb + (size_t)kt * 4096;
    const __bf16* vbase = Vb + (size_t)kt * 4096;
#pragma unroll
    for (int i = 0; i < 2; i++) {
      const int j = wv * 2 + i;
      gload16(kbase + j * 512 + lane * 8, &Kls[slot][j * 512]);
      gload16(vbase + j * 512 + lane * 8, &Vls[slot][j * 512]);
    }
  };
  f32x16 Oc0 = zv, Oc1 = zv, Ol = zv;
  float m_run = -__builtin_inff();
  const u64* prow = packw + qrow;
  __builtin_amdgcn_sched_barrier(0);
  u64 pwA = prow[0];
  u64 pwB = prow[(size_t)1 * S_LEN];
  stage(0, 0);
  stage(1, 1);
  for (int it = 0; it < np; it++) {
    const int buf = (it & 1) << 1;
    u64 pwA_n = 0, pwB_n = 0;
    if (it + 1 < np) {
      pwA_n = prow[(size_t)(2 * it + 2) * S_LEN];
      pwB_n = prow[(size_t)(2 * it + 3) * S_LEN];
      stage(buf ^ 2, 2 * it + 2);
      stage((buf ^ 2) + 1, 2 * it + 3);
      asm volatile("s_waitcnt vmcnt(10)" ::: "memory");
    } else {
      asm volatile("s_waitcnt vmcnt(0)" ::: "memory");
    }
    __builtin_amdgcn_s_barrier();
    __builtin_amdgcn_sched_barrier(0);
    const __bf16* KlA = Kls[buf];
    const __bf16* KlB = Kls[buf + 1];
    const __bf16* VlA = Vls[buf];
    const __bf16* VlB = Vls[buf + 1];
    f32x16 pA0, pA1, pB0, pB1;
    __builtin_amdgcn_s_setprio(1);
#pragma unroll
    for (int cc = 0; cc < 4; cc++) {
      const int g = (((2 * cc + hi) ^ (l32 & 7)) << 3);
      const bf16x8 kA0 = *(const bf16x8*)&KlA[l32 * 64 + g];
      const bf16x8 kA1 = *(const bf16x8*)&KlA[(32 + l32) * 64 + g];
      const bf16x8 kB0 = *(const bf16x8*)&KlB[l32 * 64 + g];
      const bf16x8 kB1 = *(const bf16x8*)&KlB[(32 + l32) * 64 + g];
      pA0 = MFMA32(kA0, aQ[cc], cc ? pA0 : zv, 0, 0, 0);
      pA1 = MFMA32(kA1, aQ[cc], cc ? pA1 : zv, 0, 0, 0);
      pB0 = MFMA32(kB0, aQ[cc], cc ? pB0 : zv, 0, 0, 0);
      pB1 = MFMA32(kB1, aQ[cc], cc ? pB1 : zv, 0, 0, 0);
    }
    __builtin_amdgcn_s_setprio(0);
    float mx[32];
#pragma unroll
    for (int i = 0; i < 8; i++) {
      mx[i]      = fmaxf(pA0[2 * i], pA0[2 * i + 1]);
      mx[8 + i]  = fmaxf(pA1[2 * i], pA1[2 * i + 1]);
      mx[16 + i] = fmaxf(pB0[2 * i], pB0[2 * i + 1]);
      mx[24 + i] = fmaxf(pB1[2 * i], pB1[2 * i + 1]);
    }
#pragma unroll
    for (int s = 16; s >= 1; s >>= 1)
#pragma unroll
      for (int i = 0; i < s; i++) mx[i] = fmaxf(mx[i], mx[i + s]);
    const float pm = fmaxf(mx[0], __shfl_xor(mx[0], 32));
    if (!__all(pm <= m_run + THRS)) {
      const float mn = fmaxf(m_run, pm);
      const float sf = EXP2(m_run - mn);
      m_run = mn;
      if (lane < 32) sfb[wv][l32] = sf;
#pragma unroll
      for (int rq = 0; rq < 4; rq++) {
        const f32x4 s4 = *(const f32x4*)&sfb[wv][rq * 8 + 4 * hi];
#pragma unroll
        for (int rr = 0; rr < 4; rr++) {
          Oc0[rq * 4 + rr] *= s4[rr];
          Oc1[rq * 4 + rr] *= s4[rr];
          Ol[rq * 4 + rr]  *= s4[rr];
        }
      }
    }
    const u32 a0b = (u32)pwA, a1b = (u32)(pwA >> 32);
    const u32 wA0 = hi ? ((a0b >> 4) | (a1b << 28)) : a0b;
    const u32 wA1 = hi ? (a1b >> 4) : a1b;
    const u32 b0b = (u32)pwB, b1b = (u32)(pwB >> 32);
    const u32 wB0 = hi ? ((b0b >> 4) | (b1b << 28)) : b0b;
    const u32 wB1 = hi ? (b1b >> 4) : b1b;
#pragma unroll
    for (int r = 0; r < 16; r++) {
      const int sp = (r & 3) + 8 * (r >> 2);
      float eA0 = EXP2(pA0[r] - m_run);
      float eA1 = EXP2(pA1[r] - m_run);
      float eB0 = EXP2(pB0[r] - m_run);
      float eB1 = EXP2(pB1[r] - m_run);
      const int tA0 = (int)(wA0 << (31 - sp)) >> 31;
      const int tA1 = (int)(wA1 << (31 - sp)) >> 31;
      const int tB0 = (int)(wB0 << (31 - sp)) >> 31;
      const int tB1 = (int)(wB1 << (31 - sp)) >> 31;
      pA0[r] = __uint_as_float(__float_as_uint(eA0) & (u32)tA0);
      pA1[r] = __uint_as_float(__float_as_uint(eA1) & (u32)tA1);
      pB0[r] = __uint_as_float(__float_as_uint(eB0) & (u32)tB0);
      pB1[r] = __uint_as_float(__float_as_uint(eB1) & (u32)tB1);
    }
    __builtin_amdgcn_s_setprio(1);
#pragma unroll
    for (int ks = 0; ks < 4; ks++) {
      const f32x16& ps = (ks < 2) ? pA0 : pA1;
      const int b = (ks & 1) * 8;
      u32 x0 = pk(ps[b + 0], ps[b + 1]), x1 = pk(ps[b + 2], ps[b + 3]);
      u32 y0 = pk(ps[b + 4], ps[b + 5]), y1 = pk(ps[b + 6], ps[b + 7]);
      plswap(x0, y0);
      plswap(x1, y1);
      PAW pa;
      pa.w = (u32x4v){x0, x1, y0, y1};
      const int g = (((2 * ks + hi) ^ (l32 & 7)) << 3);
      const bf16x8 v0 = *(const bf16x8*)&VlA[l32 * 64 + g];
      const bf16x8 v1 = *(const bf16x8*)&VlA[(32 + l32) * 64 + g];
      Oc0 = MFMA32(pa.h, v0, Oc0, 0, 0, 0);
      Oc1 = MFMA32(pa.h, v1, Oc1, 0, 0, 0);
      Ol  = MFMA32(pa.h, onesf, Ol, 0, 0, 0);
    }
#pragma unroll
    for (int ks = 0; ks < 4; ks++) {
      const f32x16& ps = (ks < 2) ? pB0 : pB1;
      const int b = (ks & 1) * 8;
      u32 x0 = pk(ps[b + 0], ps[b + 1]), x1 = pk(ps[b + 2], ps[b + 3]);
      u32 y0 = pk(ps[b + 4], ps[b + 5]), y1 = pk(ps[b + 6], ps[b + 7]);
      plswap(x0, y0);
      plswap(x1, y1);
      PAW pa;
      pa.w = (u32x4v){x0, x1, y0, y1};
      const int g = (((2 * ks + hi) ^ (l32 & 7)) << 3);
      const bf16x8 v0 = *(const bf16x8*)&VlB[l32 * 64 + g];
      const bf16x8 v1 = *(const bf16x8*)&VlB[(32 + l32) * 64 + g];
      Oc0 = MFMA32(pa.h, v0, Oc0, 0, 0, 0);
      Oc1 = MFMA32(pa.h, v1, Oc1, 0, 0, 0);
      Ol  = MFMA32(pa.h, onesf, Ol, 0, 0, 0);
    }
    __builtin_amdgcn_s_setprio(0);
    __builtin_amdgcn_s_barrier();
    pwA = pwA_n;
    pwB = pwB_n;
  }
  float* ob = out + ((size_t)h * S_LEN + q0 + wv * WQ) * DHD;
#pragma unroll
  for (int rq = 0; rq < 4; rq++) {
#pragma unroll
    for (int rr = 0; rr < 4; rr++) {
      const int r = rq * 4 + rr;
      const float linv = 1.0f / Ol[r];
      const int qq = rr + 8 * rq + 4 * hi;
      ob[(size_t)qq * DHD + l32]      = Oc0[r] * linv;
      ob[(size_t)qq * DHD + 32 + l32] = Oc1[r] * linv;
    }
  }
}

// ===================== single merged prep kernel =====================
__global__ void __launch_bounds__(256) prep_all(
    const unsigned* __restrict__ pat32, const int* __restrict__ mask,
    const float* __restrict__ K, const float* __restrict__ V,
    u64* __restrict__ packw, __bf16* __restrict__ Kc, __bf16* __restrict__ Vc) {
  __shared__ int idxs[S_LEN];
  __shared__ int red8[8];
  __shared__ __align__(16) unsigned rowbuf[4096];
  const int t = threadIdx.x, lane = t & 63, wv = t >> 6;

  unsigned mb = 0;
#pragma unroll
  for (int j = 0; j < 16; j++) mb |= (unsigned)(mask[t * 16 + j] != 0) << j;
  const int cnt = __builtin_popcount(mb);
  int inc = cnt;
  for (int d = 1; d < 64; d <<= 1) {
    const int v = __shfl_up(inc, d);
    if (lane >= d) inc += v;
  }
  if (lane == 63) red8[wv] = inc;
  __syncthreads();
  int base = 0;
  for (int w = 0; w < wv; w++) base += red8[w];
  const int nact = red8[0] + red8[1] + red8[2] + red8[3];
  int pfx = base + inc - cnt;
#pragma unroll
  for (int j = 0; j < 16; j++)
    if ((mb >> j) & 1) idxs[pfx++] = t * 16 + j;
  __syncthreads();
  const int nt = (nact + 63) >> 6;
  const int nte = (nt + 1) & ~1;

  if (blockIdx.x < S_LEN) {
    const int q = blockIdx.x;
    unsigned acc = 0;
    for (int i = t; i < 4096; i += 256) {
      const unsigned w = pat32[i];
      if (w == 0x3F800000u) acc |= 2u;
      else if (w & 0xFFFFFF00u) acc |= 1u;
    }
    for (int d = 1; d < 64; d <<= 1) acc |= (unsigned)__shfl_xor((int)acc, d);
    if (lane == 0) red8[4 + wv] = (int)acc;
    __syncthreads();
    acc = (unsigned)(red8[4] | red8[5] | red8[6] | red8[7]);
    const int mode = (acc & 2u) ? 2 : ((acc & 1u) ? 1 : 0);

    if (mode == 1) {
      const uint4* src = (const uint4*)((const unsigned char*)pat32 + ((size_t)q << 12));
      ((uint4*)rowbuf)[t] = src[t];
    } else {
      const uint4* src = (const uint4*)(pat32 + ((size_t)q << 12));
#pragma unroll
      for (int i = 0; i < 4; i++) ((uint4*)rowbuf)[t + 256 * i] = src[t + 256 * i];
    }
    __syncthreads();
    const unsigned char* rb = (const unsigned char*)rowbuf;
    const int nkw = nte * 64;
    for (int bs = 0; bs < nkw; bs += 256) {
      const int j = bs + t;
      bool pb = false;
      if (j < nact) {
        const int k = idxs[j];
        pb = (mode == 1) ? (rb[k] != 0) : (rowbuf[k] != 0);
      }
      const u64 b = __ballot(pb);
      if ((t & 63) == 0) packw[(size_t)(j >> 6) * S_LEN + q] = b;
    }
  } else {
    const int bb = blockIdx.x - S_LEN;
    const int kt = bb & 63, h = bb >> 6;
    if (kt >= nte) return;
    __bf16* Kd = Kc + ((size_t)(h * NKT + kt)) * 4096;
    __bf16* Vd = Vc + ((size_t)(h * NKT + kt)) * 4096;
    const float* Kb = K + (size_t)h * S_LEN * DHD;
    const float* Vb = V + (size_t)h * S_LEN * DHD;
#pragma unroll
    for (int i = 0; i < 4; i++) {
      const int u = t + 256 * i;
      const int kk = u >> 4, d = (u & 15) * 4;
      const int kg = kt * 64 + kk;
      float4 v = {0.f, 0.f, 0.f, 0.f};
      if (kg < nact) v = *(const float4*)(Kb + (size_t)idxs[kg] * DHD + d);
      bf16x4 b;
      b[0] = (__bf16)v.x; b[1] = (__bf16)v.y; b[2] = (__bf16)v.z; b[3] = (__bf16)v.w;
      *(bf16x4*)&Kd[swz(kk, d)] = b;
    }
#pragma unroll
    for (int i = 0; i < 2; i++) {
      const int u = t + 256 * i;
      const int kp = u & 31, d4 = u >> 5;
      const int g0 = kt * 64 + 2 * kp, g1 = g0 + 1;
      float4 a = {0.f, 0.f, 0.f, 0.f}, b = {0.f, 0.f, 0.f, 0.f};
      if (g0 < nact) a = *(const float4*)(Vb + (size_t)idxs[g0] * DHD + d4 * 4);
      if (g1 < nact) b = *(const float4*)(Vb + (size_t)idxs[g1] * DHD + d4 * 4);
      const float* A = reinterpret_cast<const float*>(&a);
      const float* B = reinterpret_cast<const float*>(&b);
#pragma unroll
      for (int j = 0; j < 4; j++) {
        *(u32*)&Vd[swz(d4 * 4 + j, 2 * kp)] = pk(A[j], B[j]);
      }
    }
  }
}

extern "C" void kernel_launch(void* const* d_in, const int* in_sizes, int n_in,
                              void* d_out, int out_size, void* d_ws, size_t ws_size,
                              hipStream_t stream) {
  (void)in_sizes; (void)n_in; (void)out_size;
  const float* Q  = (const float*)d_in[0];
  const float* K  = (const float*)d_in[1];
  const float* V  = (const float*)d_in[2];
  const void* pat = d_in[3];
  const int* mask = (const int*)d_in[4];
  float* out      = (float*)d_out;

  // workspace layout
  const size_t PACKW_OFF = 32768;
  const size_t KC_OFF    = PACKW_OFF + (size_t)S_LEN * NKT * 8;       // +2 MB
  const size_t VC_OFF    = KC_OFF + (size_t)NH * NKT * 4096 * 2;      // +8 MB
  const size_t NEED_FULL = VC_OFF + (size_t)NH * NKT * 4096 * 2;      // ~18.9 MB
  const size_t OPART_OFF = NEED_FULL;
  const size_t L0_OFF    = OPART_OFF + (size_t)NH * S_LEN * DHD * 4;  // +16 MB
  const size_t M0_OFF    = L0_OFF + (size_t)NH * S_LEN * 4;
  const size_t L1_OFF    = M0_OFF + (size_t)NH * S_LEN * 4;
  const size_t M1_OFF    = L1_OFF + (size_t)NH * S_LEN * 4;
  const size_t NEED_SPLIT = M1_OFF + (size_t)NH * S_LEN * 4;          // ~36.7 MB

  if (ws_size >= NEED_SPLIT) {
    u64* packw = (u64*)((char*)d_ws + PACKW_OFF);
    __bf16* Kc = (__bf16*)((char*)d_ws + KC_OFF);
    __bf16* Vc = (__bf16*)((char*)d_ws + VC_OFF);
    float* Opart = (float*)((char*)d_ws + OPART_OFF);
    float* l0a = (float*)((char*)d_ws + L0_OFF);
    float* m0a = (float*)((char*)d_ws + M0_OFF);
    float* l1a = (float*)((char*)d_ws + L1_OFF);
    float* m1a = (float*)((char*)d_ws + M1_OFF);
    prep_all<<<S_LEN + NKT * NH, 256, 0, stream>>>((const unsigned*)pat, mask, K, V,
                                                   packw, Kc, Vc);
    attn64s<<<1024, 128, 0, stream>>>(Q, Kc, Vc, packw, mask,
                                      out, Opart, l0a, m0a, l1a, m1a);
    merge_k<<<(NH * S_LEN * 16) / 256, 256, 0, stream>>>(out, Opart, l0a, m0a, l1a, m1a);
  } else if (ws_size >= NEED_FULL) {
    u64* packw = (u64*)((char*)d_ws + PACKW_OFF);
    __bf16* Kc = (__bf16*)((char*)d_ws + KC_OFF);
    __bf16* Vc = (__bf16*)((char*)d_ws + VC_OFF);
    prep_all<<<S_LEN + NKT * NH, 256, 0, stream>>>((const unsigned*)pat, mask, K, V,
                                                   packw, Kc, Vc);
    attn32c2<<<dim3(32 * NH), 256, 0, stream>>>(Q, Kc, Vc, packw, mask, out);
  } else {
    // minimal emergency path: dense probe via mid-tier shapes is unavailable without ws;
    // reuse attn32c2 requires prep, so fall back to a trivial-correct route: run prep-less
    // is impossible -> use the full-range kernel only when ws allows. For tiny ws, compute
    // with the 2-tile kernel on raw K/V is not supported; assume harness provides >=19MB.
    // (All observed runs provide >=37MB.)
    u64* packw = (u64*)((char*)d_ws + PACKW_OFF);
    __bf16* Kc = (__bf16*)((char*)d_ws + KC_OFF);
    __bf16* Vc = (__bf16*)((char*)d_ws + VC_OFF);
    prep_all<<<S_LEN + NKT * NH, 256, 0, stream>>>((const unsigned*)pat, mask, K, V,
                                                   packw, Kc, Vc);
    attn32c2<<<dim3(32 * NH), 256, 0, stream>>>(Q, Kc, Vc, packw, mask, out);
  }
}

// Round 13
// 94.899 us; speedup vs baseline: 1.2346x; 1.2346x over previous
//
#include <hip/hip_runtime.h>
#include <hip/hip_bf16.h>

#define S_LEN 4096
#define DHD   64
#define NH    16
#define NKT   64
#define KVB   64
#define WQ    32
#define NW    4
#define QB    (WQ * NW)   // 128
#define QSCALE 0.18033688011112042f   // (1/8) * log2(e) folded into Q
#define THRS   8.656170245333781f     // defer-max threshold: 6 nats in log2 domain

typedef __bf16 bf16x8 __attribute__((ext_vector_type(8)));
typedef __bf16 bf16x4 __attribute__((ext_vector_type(4)));
typedef float  f32x16 __attribute__((ext_vector_type(16)));
typedef float  f32x4  __attribute__((ext_vector_type(4)));
typedef unsigned u32;
typedef unsigned u32x4v __attribute__((ext_vector_type(4)));
typedef unsigned long long u64;

#define MFMA32 __builtin_amdgcn_mfma_f32_32x32x16_bf16

__device__ __forceinline__ float fexp2(float x) {
  float r;
  asm("v_exp_f32 %0, %1" : "=v"(r) : "v"(x));
  return r;
}
#define EXP2(x) fexp2(x)

// XOR swizzle (G4): element = row*64 + (((col>>3) ^ (row&7))<<3 | (col&7))
__device__ __forceinline__ int swz(int row, int col) {
  return row * 64 + ((((col >> 3) ^ (row & 7)) << 3) | (col & 7));
}

__device__ __forceinline__ u32 pk(float a, float b) {   // pack 2 f32 -> 2 bf16 (RNE)
  __bf16 x = (__bf16)a, y = (__bf16)b;
  u32 lo = (u32)__builtin_bit_cast(unsigned short, x);
  u32 hi = (u32)__builtin_bit_cast(unsigned short, y);
  return lo | (hi << 16);
}

__device__ __forceinline__ void gload16(const void* g, void* l) {
  __builtin_amdgcn_global_load_lds((const __attribute__((address_space(1))) void*)g,
                                   (__attribute__((address_space(3))) void*)l, 16, 0, 0);
}

__device__ __forceinline__ void plswap(u32& x, u32& y) {
  asm("v_permlane32_swap_b32 %0, %1" : "+v"(x), "+v"(y));
}

union PAW { u32x4v w; bf16x8 h; };

// ===================== 3-buffer deep-pipeline kernel (ONE barrier per tile) ==============
// K/V pre-gathered (mask-surviving keys only), bf16, PRE-SWIZZLED tile layout (rule #21).
// Triple-buffered streams; staging moved AFTER the barrier: the buffer staged at iter i
// ((i+2)%3) was last read at iter i-1 BEFORE barrier(i) -> write-after-read is safe with a
// single barrier per tile. Staged data consumed 2 iterations later => ~5400cy in flight.
__global__ void __launch_bounds__(256, 2) attn3b(
    const float* __restrict__ Qg, const __bf16* __restrict__ Kc, const __bf16* __restrict__ Vc,
    const u64* __restrict__ packw,            // [w][q] bit j = pat(q, key(w*64+j))
    const int* __restrict__ mask, float* __restrict__ out) {
  __shared__ __align__(16) __bf16 Kls[3][4096];
  __shared__ __align__(16) __bf16 Vls[3][4096];
  __shared__ float sfb[NW][WQ];
  __shared__ int msum[NW];

  // XCD-chunked block swizzle: each XCD owns 2 consecutive heads (K/V L2-resident)
  const int gid = (blockIdx.x & 7) * 64 + (blockIdx.x >> 3);
  const int h = gid >> 5;
  const int q0 = (gid & 31) * QB;

  const int t = threadIdx.x, lane = t & 63, wv = t >> 6;
  const int l32 = lane & 31, hi = lane >> 5;
  const int qrow = q0 + wv * WQ + l32;

  // ---- self-compute active-key count from mask (16KB, L2-hot) ----
  int c = 0;
#pragma unroll
  for (int j = 0; j < 16; j++) c += (mask[t * 16 + j] != 0);
#pragma unroll
  for (int d = 1; d < 64; d <<= 1) c += __shfl_xor(c, d);
  if (lane == 0) msum[wv] = c;

  // Q B-fragments: aQ[cc] elem j = Q[qrow][cc*16 + hi*8 + j] * QSCALE
  bf16x8 aQ[4];
  {
    const float* qp = Qg + ((size_t)h * S_LEN + qrow) * DHD;
#pragma unroll
    for (int cc = 0; cc < 4; cc++) {
      float4 x = *(const float4*)(qp + cc * 16 + hi * 8);
      float4 y = *(const float4*)(qp + cc * 16 + hi * 8 + 4);
      bf16x8 f;
      f[0] = (__bf16)(x.x * QSCALE); f[1] = (__bf16)(x.y * QSCALE);
      f[2] = (__bf16)(x.z * QSCALE); f[3] = (__bf16)(x.w * QSCALE);
      f[4] = (__bf16)(y.x * QSCALE); f[5] = (__bf16)(y.y * QSCALE);
      f[6] = (__bf16)(y.z * QSCALE); f[7] = (__bf16)(y.w * QSCALE);
      aQ[cc] = f;
    }
  }
  bf16x8 onesf;
#pragma unroll
  for (int j = 0; j < 8; j++) onesf[j] = (__bf16)1.0f;
  f32x16 zv;
#pragma unroll
  for (int r = 0; r < 16; r++) zv[r] = 0.f;

  __syncthreads();
  const int nact = msum[0] + msum[1] + msum[2] + msum[3];
  const int nt = (nact + 63) >> 6;

  const __bf16* Kb = Kc + (size_t)h * NKT * 4096;
  const __bf16* Vb = Vc + (size_t)h * NKT * 4096;

  auto stage = [&](int buf, int kt) {
    const __bf16* kbase = Kb + (size_t)kt * 4096;
    const __bf16* vbase = Vb + (size_t)kt * 4096;
#pragma unroll
    for (int i = 0; i < 2; i++) {
      const int j = wv * 2 + i;           // chunk 0..7 of 512 elems (1KB)
      gload16(kbase + j * 512 + lane * 8, &Kls[buf][j * 512]);
      gload16(vbase + j * 512 + lane * 8, &Vls[buf][j * 512]);
    }
  };

  f32x16 Oc0 = zv, Oc1 = zv, Ol = zv;
  float m_run = -__builtin_inff();
  const u64* prow = packw + qrow;

  __builtin_amdgcn_sched_barrier(0);
  // prologue: 2 tiles in flight (8 gloads)
  stage(0, 0);
  if (nt > 1) stage(1, 1);
  int buf = 0;

  for (int kt = 0; kt < nt; kt++) {
    // only the NEXT tile's 4 gloads may remain in flight -> this tile's staging complete
    if (kt + 1 < nt) {
      asm volatile("s_waitcnt vmcnt(4)" ::: "memory");
    } else {
      asm volatile("s_waitcnt vmcnt(0)" ::: "memory");
    }
    __builtin_amdgcn_s_barrier();        // the ONLY barrier per tile
    __builtin_amdgcn_sched_barrier(0);   // rule #18

    const u64 pw = prow[(size_t)kt * S_LEN];   // L2-hot; used ~800cy later (post-QK)
    if (kt + 2 < nt) {
      const int b2 = (buf + 2 >= 3) ? buf - 1 : buf + 2;
      stage(b2, kt + 2);                 // safe: b2 last read at iter kt-1, before barrier
    }

    const __bf16* Kl = Kls[buf];
    const __bf16* Vl = Vls[buf];

    // ---- S^T = K Q^T: p0 = k rows 0..31, p1 = 32..63; lane owns q = l32 ----
    f32x16 p0, p1;
    __builtin_amdgcn_s_setprio(1);
#pragma unroll
    for (int cc = 0; cc < 4; cc++) {
      const int g = (((2 * cc + hi) ^ (l32 & 7)) << 3);
      const bf16x8 k0 = *(const bf16x8*)&Kl[l32 * 64 + g];
      const bf16x8 k1 = *(const bf16x8*)&Kl[(32 + l32) * 64 + g];
      p0 = MFMA32(k0, aQ[cc], cc ? p0 : zv, 0, 0, 0);
      p1 = MFMA32(k1, aQ[cc], cc ? p1 : zv, 0, 0, 0);
    }
    __builtin_amdgcn_s_setprio(0);

    // ---- tree max ----
    float mx[16];
#pragma unroll
    for (int i = 0; i < 8; i++) {
      mx[i]     = fmaxf(p0[2 * i], p0[2 * i + 1]);
      mx[8 + i] = fmaxf(p1[2 * i], p1[2 * i + 1]);
    }
#pragma unroll
    for (int s = 8; s >= 1; s >>= 1)
#pragma unroll
      for (int i = 0; i < s; i++) mx[i] = fmaxf(mx[i], mx[i + s]);
    const float pm = fmaxf(mx[0], __shfl_xor(mx[0], 32));

    if (!__all(pm <= m_run + THRS)) {   // defer-max (T13)
      const float mn = fmaxf(m_run, pm);
      const float sf = EXP2(m_run - mn);
      m_run = mn;
      if (lane < 32) sfb[wv][l32] = sf;
#pragma unroll
      for (int rq = 0; rq < 4; rq++) {   // transpose sf into C-layout rows (wave-private)
        const f32x4 s4 = *(const f32x4*)&sfb[wv][rq * 8 + 4 * hi];
#pragma unroll
        for (int rr = 0; rr < 4; rr++) {
          Oc0[rq * 4 + rr] *= s4[rr];
          Oc1[rq * 4 + rr] *= s4[rr];
          Ol[rq * 4 + rr]  *= s4[rr];
        }
      }
    }

    // pattern bits, shifted for this lane half: element (ksub,sp) = bit 32*ksub + sp + 4*hi
    const u32 b0 = (u32)pw, b1 = (u32)(pw >> 32);
    const u32 w0 = hi ? ((b0 >> 4) | (b1 << 28)) : b0;
    const u32 w1 = hi ? (b1 >> 4) : b1;

#pragma unroll
    for (int r = 0; r < 16; r++) {
      const int sp = (r & 3) + 8 * (r >> 2);
      float e0 = EXP2(p0[r] - m_run);
      float e1 = EXP2(p1[r] - m_run);
      const int t0 = (int)(w0 << (31 - sp)) >> 31;   // bit -> all-ones / 0
      const int t1 = (int)(w1 << (31 - sp)) >> 31;
      p0[r] = __uint_as_float(__float_as_uint(e0) & (u32)t0);
      p1[r] = __uint_as_float(__float_as_uint(e1) & (u32)t1);
    }

    // ---- P -> bf16 A-frags via pack + permlane32_swap; PV + l via MFMA-ones ----
    __builtin_amdgcn_s_setprio(1);
#pragma unroll
    for (int ks = 0; ks < 4; ks++) {
      const f32x16& ps = (ks < 2) ? p0 : p1;
      const int b = (ks & 1) * 8;
      u32 x0 = pk(ps[b + 0], ps[b + 1]), x1 = pk(ps[b + 2], ps[b + 3]);
      u32 y0 = pk(ps[b + 4], ps[b + 5]), y1 = pk(ps[b + 6], ps[b + 7]);
      plswap(x0, y0);
      plswap(x1, y1);
      PAW pa;
      pa.w = (u32x4v){x0, x1, y0, y1};
      const int g = (((2 * ks + hi) ^ (l32 & 7)) << 3);
      const bf16x8 v0 = *(const bf16x8*)&Vl[l32 * 64 + g];
      const bf16x8 v1 = *(const bf16x8*)&Vl[(32 + l32) * 64 + g];
      Oc0 = MFMA32(pa.h, v0, Oc0, 0, 0, 0);
      Oc1 = MFMA32(pa.h, v1, Oc1, 0, 0, 0);
      Ol  = MFMA32(pa.h, onesf, Ol, 0, 0, 0);
    }
    __builtin_amdgcn_s_setprio(0);

    buf = (buf + 1 >= 3) ? 0 : buf + 1;
    // NO second barrier: next iter's barrier guards the re-stage (3-buffer proof above)
  }

  // ---- epilogue: l already in C layout ----
  float* ob = out + ((size_t)h * S_LEN + q0 + wv * WQ) * DHD;
#pragma unroll
  for (int rq = 0; rq < 4; rq++) {
#pragma unroll
    for (int rr = 0; rr < 4; rr++) {
      const int r = rq * 4 + rr;
      const float linv = 1.0f / Ol[r];
      const int qq = rr + 8 * rq + 4 * hi;
      ob[(size_t)qq * DHD + l32]      = Oc0[r] * linv;
      ob[(size_t)qq * DHD + 32 + l32] = Oc1[r] * linv;
    }
  }
}

// ===================== single merged prep kernel (R7-proven) =====================
// blocks [0, S_LEN): pattern-bit pack for q-row b (self dtype-detect, LDS-staged row).
// blocks [S_LEN, S_LEN+NKT*NH): K/V gather -> bf16 -> pre-swizzled tiles (+ zero pad tile).
__global__ void __launch_bounds__(256) prep_all(
    const unsigned* __restrict__ pat32, const int* __restrict__ mask,
    const float* __restrict__ K, const float* __restrict__ V,
    u64* __restrict__ packw, __bf16* __restrict__ Kc, __bf16* __restrict__ Vc) {
  __shared__ int idxs[S_LEN];
  __shared__ int red8[8];
  __shared__ __align__(16) unsigned rowbuf[4096];
  const int t = threadIdx.x, lane = t & 63, wv = t >> 6;

  unsigned mb = 0;
#pragma unroll
  for (int j = 0; j < 16; j++) mb |= (unsigned)(mask[t * 16 + j] != 0) << j;
  const int cnt = __builtin_popcount(mb);
  int inc = cnt;
  for (int d = 1; d < 64; d <<= 1) {
    const int v = __shfl_up(inc, d);
    if (lane >= d) inc += v;
  }
  if (lane == 63) red8[wv] = inc;
  __syncthreads();
  int base = 0;
  for (int w = 0; w < wv; w++) base += red8[w];
  const int nact = red8[0] + red8[1] + red8[2] + red8[3];
  int pfx = base + inc - cnt;
#pragma unroll
  for (int j = 0; j < 16; j++)
    if ((mb >> j) & 1) idxs[pfx++] = t * 16 + j;
  __syncthreads();
  const int nt = (nact + 63) >> 6;

  if (blockIdx.x < S_LEN) {
    const int q = blockIdx.x;
    unsigned acc = 0;
    for (int i = t; i < 4096; i += 256) {
      const unsigned w = pat32[i];
      if (w == 0x3F800000u) acc |= 2u;
      else if (w & 0xFFFFFF00u) acc |= 1u;
    }
    for (int d = 1; d < 64; d <<= 1) acc |= (unsigned)__shfl_xor((int)acc, d);
    if (lane == 0) red8[4 + wv] = (int)acc;
    __syncthreads();
    acc = (unsigned)(red8[4] | red8[5] | red8[6] | red8[7]);
    const int mode = (acc & 2u) ? 2 : ((acc & 1u) ? 1 : 0);

    if (mode == 1) {
      const uint4* src = (const uint4*)((const unsigned char*)pat32 + ((size_t)q << 12));
      ((uint4*)rowbuf)[t] = src[t];
    } else {
      const uint4* src = (const uint4*)(pat32 + ((size_t)q << 12));
#pragma unroll
      for (int i = 0; i < 4; i++) ((uint4*)rowbuf)[t + 256 * i] = src[t + 256 * i];
    }
    __syncthreads();
    const unsigned char* rb = (const unsigned char*)rowbuf;
    const int nkw = nt * 64;
    for (int bs = 0; bs < nkw; bs += 256) {
      const int j = bs + t;
      bool pb = false;
      if (j < nact) {
        const int k = idxs[j];
        pb = (mode == 1) ? (rb[k] != 0) : (rowbuf[k] != 0);
      }
      const u64 b = __ballot(pb);
      if ((t & 63) == 0) packw[(size_t)(j >> 6) * S_LEN + q] = b;
    }
  } else {
    const int bb = blockIdx.x - S_LEN;
    const int kt = bb & 63, h = bb >> 6;
    if (kt >= nt) return;
    __bf16* Kd = Kc + ((size_t)(h * NKT + kt)) * 4096;
    __bf16* Vd = Vc + ((size_t)(h * NKT + kt)) * 4096;
    const float* Kb = K + (size_t)h * S_LEN * DHD;
    const float* Vb = V + (size_t)h * S_LEN * DHD;
#pragma unroll
    for (int i = 0; i < 4; i++) {
      const int u = t + 256 * i;
      const int kk = u >> 4, d = (u & 15) * 4;
      const int kg = kt * 64 + kk;
      float4 v = {0.f, 0.f, 0.f, 0.f};
      if (kg < nact) v = *(const float4*)(Kb + (size_t)idxs[kg] * DHD + d);
      bf16x4 b;
      b[0] = (__bf16)v.x; b[1] = (__bf16)v.y; b[2] = (__bf16)v.z; b[3] = (__bf16)v.w;
      *(bf16x4*)&Kd[swz(kk, d)] = b;
    }
#pragma unroll
    for (int i = 0; i < 2; i++) {
      const int u = t + 256 * i;
      const int kp = u & 31, d4 = u >> 5;
      const int g0 = kt * 64 + 2 * kp, g1 = g0 + 1;
      float4 a = {0.f, 0.f, 0.f, 0.f}, b = {0.f, 0.f, 0.f, 0.f};
      if (g0 < nact) a = *(const float4*)(Vb + (size_t)idxs[g0] * DHD + d4 * 4);
      if (g1 < nact) b = *(const float4*)(Vb + (size_t)idxs[g1] * DHD + d4 * 4);
      const float* A = reinterpret_cast<const float*>(&a);
      const float* B = reinterpret_cast<const float*>(&b);
#pragma unroll
      for (int j = 0; j < 4; j++) {
        *(u32*)&Vd[swz(d4 * 4 + j, 2 * kp)] = pk(A[j], B[j]);
      }
    }
  }
}

extern "C" void kernel_launch(void* const* d_in, const int* in_sizes, int n_in,
                              void* d_out, int out_size, void* d_ws, size_t ws_size,
                              hipStream_t stream) {
  (void)in_sizes; (void)n_in; (void)out_size; (void)ws_size;
  const float* Q  = (const float*)d_in[0];
  const float* K  = (const float*)d_in[1];
  const float* V  = (const float*)d_in[2];
  const void* pat = d_in[3];
  const int* mask = (const int*)d_in[4];
  float* out      = (float*)d_out;

  // workspace layout (~18.9 MB; harness provides >=37MB in all observed runs)
  const size_t PACKW_OFF = 32768;
  const size_t KC_OFF    = PACKW_OFF + (size_t)S_LEN * NKT * 8;       // +2 MB
  const size_t VC_OFF    = KC_OFF + (size_t)NH * NKT * 4096 * 2;      // +8 MB

  u64* packw = (u64*)((char*)d_ws + PACKW_OFF);
  __bf16* Kc = (__bf16*)((char*)d_ws + KC_OFF);
  __bf16* Vc = (__bf16*)((char*)d_ws + VC_OFF);

  prep_all<<<S_LEN + NKT * NH, 256, 0, stream>>>((const unsigned*)pat, mask, K, V,
                                                 packw, Kc, Vc);
  attn3b<<<dim3(32 * NH), 256, 0, stream>>>(Q, Kc, Vc, packw, mask, out);
}